// Round 17
// baseline (104.146 us; speedup 1.0000x reference)
//
#include <hip/hip_runtime.h>
#include <math.h>

#define BS 32
#define NQ 900
#define NC 1203
#define NT 100
#define SLOTS 15   // ceil(900/64)
#define K8 8
#define JBLK 512
#define NW 8
#define VCAP 3     // ARR visit cap (r16-proven)

// Static device-side scratch: no hipMalloc, graph-capture safe, fully
// rewritten every call before any read (deterministic).
__device__ float g_CT[(size_t)BS * NT * NQ];   // 11.5 MB: CT[b][t][q]
__device__ unsigned long long g_topk[(size_t)BS * NT * K8];

// packed sortable key: (monotone f32 bits) << 32 | col
__device__ __forceinline__ unsigned long long packf(float f, int col) {
    unsigned k = __float_as_uint(f);
    k = (k & 0x80000000u) ? ~k : (k | 0x80000000u);
    return ((unsigned long long)k << 32) | (unsigned)col;
}
__device__ __forceinline__ float unpack_val(unsigned long long p) {
    unsigned k = (unsigned)(p >> 32);
    unsigned bits = (k & 0x80000000u) ? (k ^ 0x80000000u) : ~k;
    return __uint_as_float(bits);
}
__device__ __forceinline__ int unpack_col(unsigned long long p) {
    return (int)(p & 0xFFFFFFFFu);
}

// ---------------------------------------------------------------------------
// Kernel 1: cost matrix (math identical to all passing rounds).
// Writes C (coalesced) AND g_CT (scattered 4B, fire-and-forget; L2 absorbs —
// the rounds-2-6-proven pattern). Replaces the separate transpose pass.
// ---------------------------------------------------------------------------
__global__ __launch_bounds__(128) void cost_kernel(
    const float* __restrict__ logits, const float* __restrict__ boxes,
    const int* __restrict__ tlabels, const float* __restrict__ tboxes,
    float* __restrict__ C)
{
    int bq = blockIdx.x;
    int b = bq / NQ, q = bq % NQ;
    int t = threadIdx.x;

    const float* pb = boxes + (size_t)(b * NQ + q) * 4;
    float pcx = pb[0], pcy = pb[1], pw = pb[2], ph = pb[3];

    if (t < NT) {
        int id = tlabels[b * NT + t];
        float x = logits[(size_t)(b * NQ + q) * NC + id];
        float prob = 1.0f / (1.0f + expf(-x));
        float neg = 0.75f * (prob * prob) * (-logf(1.0f - prob + 1e-8f));
        float pos = 0.25f * ((1.0f - prob) * (1.0f - prob)) * (-logf(prob + 1e-8f));
        float cclass = pos - neg;

        const float* tb = tboxes + (size_t)(b * NT + t) * 4;
        float tcx = tb[0], tcy = tb[1], tw = tb[2], th = tb[3];
        float cbbox = fabsf(pcx - tcx) + fabsf(pcy - tcy) + fabsf(pw - tw) + fabsf(ph - th);

        float p0 = pcx - 0.5f * pw, p1 = pcy - 0.5f * ph;
        float p2 = pcx + 0.5f * pw, p3 = pcy + 0.5f * ph;
        float t0 = tcx - 0.5f * tw, t1 = tcy - 0.5f * th;
        float t2 = tcx + 0.5f * tw, t3 = tcy + 0.5f * th;
        float area1 = (p2 - p0) * (p3 - p1);
        float area2 = (t2 - t0) * (t3 - t1);
        float ltx = fmaxf(p0, t0), lty = fmaxf(p1, t1);
        float rbx = fminf(p2, t2), rby = fminf(p3, t3);
        float wx = fmaxf(rbx - ltx, 0.0f), wy = fmaxf(rby - lty, 0.0f);
        float inter = wx * wy;
        float uni = area1 + area2 - inter;
        float iou = inter / uni;
        float l2x = fminf(p0, t0), l2y = fminf(p1, t1);
        float r2x = fmaxf(p2, t2), r2y = fmaxf(p3, t3);
        float hx = fmaxf(r2x - l2x, 0.0f), hy = fmaxf(r2y - l2y, 0.0f);
        float hull = hx * hy;
        float giou = iou - (hull - uni) / hull;

        float val = 5.0f * cbbox + 2.0f * cclass + 2.0f * (-giou);
        C[(size_t)(b * NQ + q) * NT + t] = val;
        g_CT[((size_t)b * NT + t) * NQ + q] = val;
    }
}

// ---------------------------------------------------------------------------
// Kernel 2: per-row sorted top-8 from g_CT (coalesced), one wave per row.
// ---------------------------------------------------------------------------
__global__ __launch_bounds__(64) void topk_kernel()
{
    int bi = blockIdx.x;                    // b*NT + t
    const float* row = g_CT + (size_t)bi * NQ;
    int lane = threadIdx.x;

    unsigned long long r[K8];
    #pragma unroll
    for (int m = 0; m < K8; ++m) r[m] = 0xFFFFFFFFFFFFFFFFull;

    #pragma unroll
    for (int k = 0; k < SLOTS; ++k) {
        int j = (k << 6) + lane;
        if ((k < SLOTS - 1) || (j < NQ)) {
            unsigned long long key = packf(row[j], j);
            #pragma unroll
            for (int m = 0; m < K8; ++m) {     // sorted insert, drop largest
                unsigned long long lo = key < r[m] ? key : r[m];
                unsigned long long hi = key < r[m] ? r[m] : key;
                r[m] = lo; key = hi;
            }
        }
    }
    #pragma unroll
    for (int off = 32; off; off >>= 1) {       // butterfly bitonic merge
        unsigned long long bv[K8], tmp[K8];
        #pragma unroll
        for (int m = 0; m < K8; ++m) bv[m] = __shfl_down(r[m], off);
        #pragma unroll
        for (int m = 0; m < K8; ++m) {
            unsigned long long x = bv[K8 - 1 - m];
            tmp[m] = r[m] < x ? r[m] : x;
        }
        #pragma unroll
        for (int d = 4; d; d >>= 1) {
            #pragma unroll
            for (int m = 0; m < K8; ++m) {
                if (!(m & d)) {
                    unsigned long long a = tmp[m], b2 = tmp[m | d];
                    tmp[m] = a < b2 ? a : b2;
                    tmp[m | d] = a < b2 ? b2 : a;
                }
            }
        }
        #pragma unroll
        for (int m = 0; m < K8; ++m) r[m] = tmp[m];
    }
    if (lane == 0) {
        #pragma unroll
        for (int m = 0; m < K8; ++m) g_topk[(size_t)bi * K8 + m] = r[m];
    }
}

// ---------------------------------------------------------------------------
// Kernel 3: JV solver, 512 threads (8 waves) per batch. Byte-identical to the
// passing round-16 solver (8-way batched ARR, VCAP=3, wave-0 Dijkstra).
// ---------------------------------------------------------------------------
__global__ __launch_bounds__(JBLK) void jv_kernel(
    const float* __restrict__ C,
    float* __restrict__ pred_out, float* __restrict__ tgt_out)
{
    int b = blockIdx.x;
    const float* Cb = C + (size_t)b * NQ * NT;       // cost.T[i][j] = Cb[j*NT+i]
    int tid = threadIdx.x;
    int w = tid >> 6, lane = tid & 63;
    const double INF = __builtin_huge_val();

    __shared__ double u[NT];
    __shared__ double vsh[NQ];
    __shared__ double distA[128];
    __shared__ int pathA[128];
    __shared__ int asgCols[128];
    __shared__ int pos4col[NQ];
    __shared__ int row4col[NQ];
    __shared__ int col4row[NT];
    __shared__ int aminsh[NT];
    __shared__ int freeRows[NT + 2 * NW];
    __shared__ int parked[NT];
    __shared__ int srList[140];
    __shared__ unsigned long long tksh[NT][K8];
    __shared__ unsigned char visits[NT];
    __shared__ double pm1[NW], pm2[NW];
    __shared__ int pj1[NW], prow[NW];
    __shared__ int nFreeSh, nParkSh, asgCountSh;

    // ---- phase A: init ----
    for (int j = tid; j < NQ; j += JBLK) { vsh[j] = 0.0; row4col[j] = 0x7fffffff; pos4col[j] = -1; }
    {
        const unsigned long long* src = g_topk + (size_t)b * NT * K8;
        for (int e = tid; e < NT * K8; e += JBLK) ((unsigned long long*)tksh)[e] = src[e];
    }
    for (int i = tid; i < NT; i += JBLK) { col4row[i] = -1; visits[i] = 0; }
    if (tid == 0) { nFreeSh = 0; nParkSh = 0; asgCountSh = 0; }
    __syncthreads();
    for (int i = tid; i < NT; i += JBLK) {
        unsigned long long tk = tksh[i][0];
        aminsh[i] = unpack_col(tk);
        u[i] = (double)unpack_val(tk);
    }
    __syncthreads();

    // ---- phase B: greedy claim (smallest row wins a contested column) ----
    for (int i = tid; i < NT; i += JBLK) atomicMin(&row4col[aminsh[i]], i);
    __syncthreads();
    if (tid == 0) {
        int n = 0, cnt = 0;
        for (int i = 0; i < NT; ++i) {
            int j = aminsh[i];
            if (row4col[j] == i) { col4row[i] = j; pos4col[j] = cnt; asgCols[cnt++] = j; }
            else freeRows[n++] = i;
        }
        nFreeSh = n; asgCountSh = cnt;
    }
    __syncthreads();
    for (int j = tid; j < NQ; j += JBLK)
        if (row4col[j] == 0x7fffffff) row4col[j] = -1;
    __syncthreads();

    // ---- phase C: 8-way batched ARR, compact candidates, VCAP-visit cap ----
    int guard = 0;
    while (guard++ < 300) {
        int nf = nFreeSh;                          // uniform (post-barrier)
        if (nf == 0) break;
        int take = nf < NW ? nf : NW;
        if (w < take) {
            int i = freeRows[nf - 1 - w];
            int asgCount = asgCountSh;

            double m1 = INF, m2 = INF; int j1 = -1;
            bool haveFree = (lane < K8) && (row4col[unpack_col(tksh[i][lane])] < 0);
            unsigned long long bal = __ballot(haveFree);
            if (__popcll(bal) >= 2) {
                #pragma unroll
                for (int s = 0; s < 2; ++s) {
                    int pos = lane + (s << 6);
                    if (pos < asgCount) {
                        int j = asgCols[pos];
                        double cur = (double)Cb[(size_t)j * NT + i] - vsh[j];
                        if (cur < m1) { m2 = m1; m1 = cur; j1 = j; }
                        else if (cur < m2) m2 = cur;
                    }
                }
                if (haveFree) {
                    unsigned long long tk = tksh[i][lane];
                    double cur = (double)unpack_val(tk);   // v == 0 for free cols
                    int j = unpack_col(tk);
                    if (cur < m1) { m2 = m1; m1 = cur; j1 = j; }
                    else if (cur < m2) m2 = cur;
                }
            } else {
                // fallback: full-width scan (rare)
                #pragma unroll
                for (int k = 0; k < SLOTS; ++k) {
                    int j = (k << 6) + lane;
                    if ((k < SLOTS - 1) || (j < NQ)) {
                        double cur = (double)Cb[(size_t)j * NT + i] - vsh[j];
                        if (cur < m1) { m2 = m1; m1 = cur; j1 = j; }
                        else if (cur < m2) m2 = cur;
                    }
                }
            }
            for (int off = 32; off; off >>= 1) {
                double o1 = __shfl_down(m1, off); int oj = __shfl_down(j1, off);
                double o2 = __shfl_down(m2, off);
                if (o1 < m1 || (o1 == m1 && (unsigned)oj < (unsigned)j1)) { m2 = fmin(m1, o2); m1 = o1; j1 = oj; }
                else m2 = fmin(m2, o1);
            }
            if (lane == 0) { pm1[w] = m1; pm2[w] = m2; pj1[w] = j1; prow[w] = i; }
        }
        __syncthreads();
        if (tid == 0) {
            int n = nf - take;
            int cj[NW]; int nc = 0;
            for (int k = 0; k < take; ++k) {
                int i = prow[k];
                if (visits[i] >= VCAP) { parked[nParkSh] = i; nParkSh++; continue; }
                int j1 = pj1[k];
                bool clash = false;
                for (int k2 = 0; k2 < nc; ++k2) if (cj[k2] == j1) clash = true;
                if (clash) { freeRows[n++] = i; continue; }    // stale vs same-round commit
                cj[nc++] = j1;
                visits[i]++;
                double m1 = pm1[k], m2 = pm2[k];
                u[i] = m2;
                vsh[j1] -= (m2 - m1);
                int inc = row4col[j1];
                row4col[j1] = i; col4row[i] = j1;
                if (inc >= 0) { col4row[inc] = -1; freeRows[n++] = inc; }
                else { pos4col[j1] = asgCountSh; asgCols[asgCountSh] = j1; asgCountSh++; }
            }
            nFreeSh = n;
        }
        __syncthreads();
    }
    if (tid == 0) {
        while (nFreeSh > 0) { nFreeSh--; parked[nParkSh] = freeRows[nFreeSh]; nParkSh++; }
    }
    __syncthreads();

    // ---- phase D: Dijkstra (wave 0 only; others idle at barriers) ----
    int np = nParkSh;
    for (int f = 0; f < np; ++f) {
        int curRow = parked[f];
        int asgCount = asgCountSh;
        double mvA = INF, mvB = INF;
        bool pA = false, pB = false;
        double bestFree = INF; int bfCol = -1, bfRow = -1;
        double minVal = 0.0; int i = curRow; int nSr = 1;
        if (w == 0) {
            for (int pos = lane; pos < asgCount; pos += 64) distA[pos] = INF;
            if (lane == 0) srList[0] = curRow;
        }
        __syncthreads();

        if (w == 0) {
            int g2 = 0; bool sink = false;
            while (!sink && g2++ < 120) {
                double ui = u[i];
                {
                    int pos = lane;
                    if (pos < asgCount && !pA) {
                        int j = asgCols[pos];
                        double cur = minVal + (double)Cb[(size_t)j * NT + i] - ui - vsh[j];
                        if (cur < mvA) { mvA = cur; distA[pos] = cur; pathA[pos] = i; }
                    }
                    pos = lane + 64;
                    if (pos < asgCount && !pB) {
                        int j = asgCols[pos];
                        double cur = minVal + (double)Cb[(size_t)j * NT + i] - ui - vsh[j];
                        if (cur < mvB) { mvB = cur; distA[pos] = cur; pathA[pos] = i; }
                    }
                }
                double fc = INF; int fj = -1;
                if (lane < K8) {
                    unsigned long long tk = tksh[i][lane];
                    int j = unpack_col(tk);
                    if (row4col[j] < 0) { fc = minVal + (double)unpack_val(tk) - ui; fj = j; }
                }
                if (__ballot(fc < INF) == 0ull) {
                    #pragma unroll
                    for (int k = 0; k < SLOTS; ++k) {
                        int j = (k << 6) + lane;
                        if (((k < SLOTS - 1) || (j < NQ)) && row4col[j] < 0) {
                            double cur = minVal + (double)Cb[(size_t)j * NT + i] - ui;
                            if (cur < fc) { fc = cur; fj = j; }
                        }
                    }
                }
                double pv; int ppos;
                double pva = pA ? INF : mvA, pvb = pB ? INF : mvB;
                if (pvb < pva) { pv = pvb; ppos = lane + 64; } else { pv = pva; ppos = lane; }
                for (int off = 32; off; off >>= 1) {
                    double o = __shfl_down(pv, off); int op = __shfl_down(ppos, off);
                    if (o < pv || (o == pv && op < ppos)) { pv = o; ppos = op; }
                    double of = __shfl_down(fc, off); int ofj = __shfl_down(fj, off);
                    if (of < fc || (of == fc && (unsigned)ofj < (unsigned)fj)) { fc = of; fj = ofj; }
                }
                pv = __shfl(pv, 0); ppos = __shfl(ppos, 0);
                fc = __shfl(fc, 0); fj = __shfl(fj, 0);
                if (fc < bestFree) { bestFree = fc; bfCol = fj; bfRow = i; }
                if (bestFree <= pv) { minVal = bestFree; sink = true; }
                else {
                    minVal = pv;
                    if (lane == (ppos & 63)) { if (ppos < 64) pA = true; else pB = true; }
                    i = row4col[asgCols[ppos]];
                    if (lane == 0) srList[nSr] = i;
                    nSr++;
                }
            }
            if (lane == 0) { pm1[0] = minVal; pj1[0] = bfCol; prow[0] = bfRow; pm2[0] = (double)nSr; }
        }
        __syncthreads();

        if (tid == 0) {
            double mv = pm1[0]; int ns = (int)pm2[0];
            u[curRow] += mv;
            for (int t2 = 1; t2 < ns; ++t2) {
                int ri = srList[t2];
                u[ri] += mv - distA[pos4col[col4row[ri]]];
            }
        }
        if (w == 0) {
            double mv = pm1[0];
            int pos = lane;
            if (pos < asgCount && pA) vsh[asgCols[pos]] -= mv - distA[pos];
            pos = lane + 64;
            if (pos < asgCount && pB) vsh[asgCols[pos]] -= mv - distA[pos];
        }
        if (tid == 0) {
            int j = pj1[0], ri = prow[0]; int g3 = 0;
            while (g3++ < 128) {
                row4col[j] = ri;
                int tj = col4row[ri]; col4row[ri] = j;
                if (ri == curRow) break;
                j = tj; ri = pathA[pos4col[j]];
            }
            pos4col[pj1[0]] = asgCountSh; asgCols[asgCountSh] = pj1[0]; asgCountSh++;
        }
        __syncthreads();
    }

    // ---- epilogue: rank-sort col4row, write indices ----
    for (int i2 = tid; i2 < NT; i2 += JBLK) {
        int ci = col4row[i2];
        int rank = 0;
        for (int k2 = 0; k2 < NT; ++k2) rank += (col4row[k2] < ci);
        pred_out[b * NT + rank] = (float)ci;
        tgt_out[b * NT + rank] = (float)i2;
    }
}

extern "C" void kernel_launch(void* const* d_in, const int* in_sizes, int n_in,
                              void* d_out, int out_size, void* d_ws, size_t ws_size,
                              hipStream_t stream) {
    const float* logits = (const float*)d_in[0];
    const float* boxes  = (const float*)d_in[1];
    const int*   tlab   = (const int*)d_in[2];
    const float* tboxes = (const float*)d_in[3];

    float* out  = (float*)d_out;
    float* C    = out;                                  // 32*900*100
    float* pred = out + (size_t)BS * NQ * NT;           // 32*100
    float* tgt  = pred + BS * NT;                       // 32*100

    cost_kernel<<<BS * NQ, 128, 0, stream>>>(logits, boxes, tlab, tboxes, C);
    topk_kernel<<<BS * NT, 64, 0, stream>>>();
    jv_kernel<<<BS, JBLK, 0, stream>>>(C, pred, tgt);
}

// Round 18
// 89.277 us; speedup vs baseline: 1.1666x; 1.1666x over previous
//
#include <hip/hip_runtime.h>
#include <math.h>

#define BS 32
#define NQ 900
#define NC 1203
#define NT 100
#define SLOTS 15   // ceil(900/64)
#define K8 8
#define JBLK 256
#define NW 4
#define VCAP 3     // ARR visit cap (r16-proven)

// Static device-side scratch: no hipMalloc, graph-capture safe, fully
// rewritten every call before any read (deterministic).
__device__ float g_CT[(size_t)BS * NT * NQ];   // 11.5 MB: CT[b][t][q]
__device__ unsigned long long g_topk[(size_t)BS * NT * K8];

// packed sortable key: (monotone f32 bits) << 32 | col
__device__ __forceinline__ unsigned long long packf(float f, int col) {
    unsigned k = __float_as_uint(f);
    k = (k & 0x80000000u) ? ~k : (k | 0x80000000u);
    return ((unsigned long long)k << 32) | (unsigned)col;
}
__device__ __forceinline__ float unpack_val(unsigned long long p) {
    unsigned k = (unsigned)(p >> 32);
    unsigned bits = (k & 0x80000000u) ? (k ^ 0x80000000u) : ~k;
    return __uint_as_float(bits);
}
__device__ __forceinline__ int unpack_col(unsigned long long p) {
    return (int)(p & 0xFFFFFFFFu);
}

// ---------------------------------------------------------------------------
// Kernel 1: cost matrix (math identical to all passing rounds; C write only —
// r17 proved folding the CT write here costs +14 µs).
// ---------------------------------------------------------------------------
__global__ __launch_bounds__(128) void cost_kernel(
    const float* __restrict__ logits, const float* __restrict__ boxes,
    const int* __restrict__ tlabels, const float* __restrict__ tboxes,
    float* __restrict__ C)
{
    int bq = blockIdx.x;
    int b = bq / NQ, q = bq % NQ;
    int t = threadIdx.x;

    const float* pb = boxes + (size_t)(b * NQ + q) * 4;
    float pcx = pb[0], pcy = pb[1], pw = pb[2], ph = pb[3];

    if (t < NT) {
        int id = tlabels[b * NT + t];
        float x = logits[(size_t)(b * NQ + q) * NC + id];
        float prob = 1.0f / (1.0f + expf(-x));
        float neg = 0.75f * (prob * prob) * (-logf(1.0f - prob + 1e-8f));
        float pos = 0.25f * ((1.0f - prob) * (1.0f - prob)) * (-logf(prob + 1e-8f));
        float cclass = pos - neg;

        const float* tb = tboxes + (size_t)(b * NT + t) * 4;
        float tcx = tb[0], tcy = tb[1], tw = tb[2], th = tb[3];
        float cbbox = fabsf(pcx - tcx) + fabsf(pcy - tcy) + fabsf(pw - tw) + fabsf(ph - th);

        float p0 = pcx - 0.5f * pw, p1 = pcy - 0.5f * ph;
        float p2 = pcx + 0.5f * pw, p3 = pcy + 0.5f * ph;
        float t0 = tcx - 0.5f * tw, t1 = tcy - 0.5f * th;
        float t2 = tcx + 0.5f * tw, t3 = tcy + 0.5f * th;
        float area1 = (p2 - p0) * (p3 - p1);
        float area2 = (t2 - t0) * (t3 - t1);
        float ltx = fmaxf(p0, t0), lty = fmaxf(p1, t1);
        float rbx = fminf(p2, t2), rby = fminf(p3, t3);
        float wx = fmaxf(rbx - ltx, 0.0f), wy = fmaxf(rby - lty, 0.0f);
        float inter = wx * wy;
        float uni = area1 + area2 - inter;
        float iou = inter / uni;
        float l2x = fminf(p0, t0), l2y = fminf(p1, t1);
        float r2x = fmaxf(p2, t2), r2y = fmaxf(p3, t3);
        float hx = fmaxf(r2x - l2x, 0.0f), hy = fmaxf(r2y - l2y, 0.0f);
        float hull = hx * hy;
        float giou = iou - (hull - uni) / hull;

        C[(size_t)(b * NQ + q) * NT + t] =
            5.0f * cbbox + 2.0f * cclass + 2.0f * (-giou);
    }
}

// ---------------------------------------------------------------------------
// Kernel 2: LDS-tiled transpose C[b][q][t] -> g_CT[b][t][q] (round-10 proven).
// ---------------------------------------------------------------------------
__global__ __launch_bounds__(256) void transpose_kernel(const float* __restrict__ C)
{
    __shared__ float tile[64][101];
    int b = blockIdx.x / 15;
    int chunk = blockIdx.x % 15;
    int q0 = chunk * 64;
    int nq = (q0 + 64 <= NQ) ? 64 : (NQ - q0);
    int tid = threadIdx.x;

    const float* Cb = C + (size_t)b * NQ * NT;
    for (int e = tid; e < nq * NT; e += 256) {
        int qq = e / NT, t = e % NT;
        tile[qq][t] = Cb[(size_t)(q0 + qq) * NT + t];
    }
    __syncthreads();
    float* CTb = g_CT + (size_t)b * NT * NQ;
    for (int e = tid; e < NT * nq; e += 256) {
        int t = e / nq, qq = e % nq;
        CTb[(size_t)t * NQ + q0 + qq] = tile[qq][t];
    }
}

// ---------------------------------------------------------------------------
// Kernel 3: per-row sorted top-8 from g_CT (coalesced), one wave per row.
// ---------------------------------------------------------------------------
__global__ __launch_bounds__(64) void topk_kernel()
{
    int bi = blockIdx.x;                    // b*NT + t
    const float* row = g_CT + (size_t)bi * NQ;
    int lane = threadIdx.x;

    unsigned long long r[K8];
    #pragma unroll
    for (int m = 0; m < K8; ++m) r[m] = 0xFFFFFFFFFFFFFFFFull;

    #pragma unroll
    for (int k = 0; k < SLOTS; ++k) {
        int j = (k << 6) + lane;
        if ((k < SLOTS - 1) || (j < NQ)) {
            unsigned long long key = packf(row[j], j);
            #pragma unroll
            for (int m = 0; m < K8; ++m) {     // sorted insert, drop largest
                unsigned long long lo = key < r[m] ? key : r[m];
                unsigned long long hi = key < r[m] ? r[m] : key;
                r[m] = lo; key = hi;
            }
        }
    }
    #pragma unroll
    for (int off = 32; off; off >>= 1) {       // butterfly bitonic merge
        unsigned long long bv[K8], tmp[K8];
        #pragma unroll
        for (int m = 0; m < K8; ++m) bv[m] = __shfl_down(r[m], off);
        #pragma unroll
        for (int m = 0; m < K8; ++m) {
            unsigned long long x = bv[K8 - 1 - m];
            tmp[m] = r[m] < x ? r[m] : x;
        }
        #pragma unroll
        for (int d = 4; d; d >>= 1) {
            #pragma unroll
            for (int m = 0; m < K8; ++m) {
                if (!(m & d)) {
                    unsigned long long a = tmp[m], b2 = tmp[m | d];
                    tmp[m] = a < b2 ? a : b2;
                    tmp[m | d] = a < b2 ? b2 : a;
                }
            }
        }
        #pragma unroll
        for (int m = 0; m < K8; ++m) r[m] = tmp[m];
    }
    if (lane == 0) {
        #pragma unroll
        for (int m = 0; m < K8; ++m) g_topk[(size_t)bi * K8 + m] = r[m];
    }
}

// ---------------------------------------------------------------------------
// Kernel 4: JV solver, 256 threads (4 waves) per batch. r16 semantics
// (batched ARR + VCAP=3 + wave-0 Dijkstra); 4 waves since batching is
// saturated past 4 (r13 vs r14) and barriers/idle-waves are cheaper.
// ---------------------------------------------------------------------------
__global__ __launch_bounds__(JBLK) void jv_kernel(
    const float* __restrict__ C,
    float* __restrict__ pred_out, float* __restrict__ tgt_out)
{
    int b = blockIdx.x;
    const float* Cb = C + (size_t)b * NQ * NT;       // cost.T[i][j] = Cb[j*NT+i]
    int tid = threadIdx.x;
    int w = tid >> 6, lane = tid & 63;
    const double INF = __builtin_huge_val();

    __shared__ double u[NT];
    __shared__ double vsh[NQ];
    __shared__ double distA[128];
    __shared__ int pathA[128];
    __shared__ int asgCols[128];
    __shared__ int pos4col[NQ];
    __shared__ int row4col[NQ];
    __shared__ int col4row[NT];
    __shared__ int aminsh[NT];
    __shared__ int freeRows[NT + 2 * NW];
    __shared__ int parked[NT];
    __shared__ int srList[140];
    __shared__ unsigned long long tksh[NT][K8];
    __shared__ unsigned char visits[NT];
    __shared__ double pm1[NW], pm2[NW];
    __shared__ int pj1[NW], prow[NW];
    __shared__ int nFreeSh, nParkSh, asgCountSh;

    // ---- phase A: init ----
    for (int j = tid; j < NQ; j += JBLK) { vsh[j] = 0.0; row4col[j] = 0x7fffffff; pos4col[j] = -1; }
    {
        const unsigned long long* src = g_topk + (size_t)b * NT * K8;
        for (int e = tid; e < NT * K8; e += JBLK) ((unsigned long long*)tksh)[e] = src[e];
    }
    for (int i = tid; i < NT; i += JBLK) { col4row[i] = -1; visits[i] = 0; }
    if (tid == 0) { nFreeSh = 0; nParkSh = 0; asgCountSh = 0; }
    __syncthreads();
    for (int i = tid; i < NT; i += JBLK) {
        unsigned long long tk = tksh[i][0];
        aminsh[i] = unpack_col(tk);
        u[i] = (double)unpack_val(tk);
    }
    __syncthreads();

    // ---- phase B: greedy claim (smallest row wins a contested column) ----
    for (int i = tid; i < NT; i += JBLK) atomicMin(&row4col[aminsh[i]], i);
    __syncthreads();
    if (tid == 0) {
        int n = 0, cnt = 0;
        for (int i = 0; i < NT; ++i) {
            int j = aminsh[i];
            if (row4col[j] == i) { col4row[i] = j; pos4col[j] = cnt; asgCols[cnt++] = j; }
            else freeRows[n++] = i;
        }
        nFreeSh = n; asgCountSh = cnt;
    }
    __syncthreads();
    for (int j = tid; j < NQ; j += JBLK)
        if (row4col[j] == 0x7fffffff) row4col[j] = -1;
    __syncthreads();

    // ---- phase C: 4-way batched ARR, compact candidates, VCAP-visit cap ----
    int guard = 0;
    while (guard++ < 300) {
        int nf = nFreeSh;                          // uniform (post-barrier)
        if (nf == 0) break;
        int take = nf < NW ? nf : NW;
        if (w < take) {
            int i = freeRows[nf - 1 - w];
            int asgCount = asgCountSh;

            double m1 = INF, m2 = INF; int j1 = -1;
            bool haveFree = (lane < K8) && (row4col[unpack_col(tksh[i][lane])] < 0);
            unsigned long long bal = __ballot(haveFree);
            if (__popcll(bal) >= 2) {
                #pragma unroll
                for (int s = 0; s < 2; ++s) {
                    int pos = lane + (s << 6);
                    if (pos < asgCount) {
                        int j = asgCols[pos];
                        double cur = (double)Cb[(size_t)j * NT + i] - vsh[j];
                        if (cur < m1) { m2 = m1; m1 = cur; j1 = j; }
                        else if (cur < m2) m2 = cur;
                    }
                }
                if (haveFree) {
                    unsigned long long tk = tksh[i][lane];
                    double cur = (double)unpack_val(tk);   // v == 0 for free cols
                    int j = unpack_col(tk);
                    if (cur < m1) { m2 = m1; m1 = cur; j1 = j; }
                    else if (cur < m2) m2 = cur;
                }
            } else {
                // fallback: full-width scan (rare)
                #pragma unroll
                for (int k = 0; k < SLOTS; ++k) {
                    int j = (k << 6) + lane;
                    if ((k < SLOTS - 1) || (j < NQ)) {
                        double cur = (double)Cb[(size_t)j * NT + i] - vsh[j];
                        if (cur < m1) { m2 = m1; m1 = cur; j1 = j; }
                        else if (cur < m2) m2 = cur;
                    }
                }
            }
            for (int off = 32; off; off >>= 1) {
                double o1 = __shfl_down(m1, off); int oj = __shfl_down(j1, off);
                double o2 = __shfl_down(m2, off);
                if (o1 < m1 || (o1 == m1 && (unsigned)oj < (unsigned)j1)) { m2 = fmin(m1, o2); m1 = o1; j1 = oj; }
                else m2 = fmin(m2, o1);
            }
            if (lane == 0) { pm1[w] = m1; pm2[w] = m2; pj1[w] = j1; prow[w] = i; }
        }
        __syncthreads();
        if (tid == 0) {
            int n = nf - take;
            int cj[NW]; int nc = 0;
            for (int k = 0; k < take; ++k) {
                int i = prow[k];
                if (visits[i] >= VCAP) { parked[nParkSh] = i; nParkSh++; continue; }
                int j1 = pj1[k];
                bool clash = false;
                for (int k2 = 0; k2 < nc; ++k2) if (cj[k2] == j1) clash = true;
                if (clash) { freeRows[n++] = i; continue; }    // stale vs same-round commit
                cj[nc++] = j1;
                visits[i]++;
                double m1 = pm1[k], m2 = pm2[k];
                u[i] = m2;
                vsh[j1] -= (m2 - m1);
                int inc = row4col[j1];
                row4col[j1] = i; col4row[i] = j1;
                if (inc >= 0) { col4row[inc] = -1; freeRows[n++] = inc; }
                else { pos4col[j1] = asgCountSh; asgCols[asgCountSh] = j1; asgCountSh++; }
            }
            nFreeSh = n;
        }
        __syncthreads();
    }
    if (tid == 0) {
        while (nFreeSh > 0) { nFreeSh--; parked[nParkSh] = freeRows[nFreeSh]; nParkSh++; }
    }
    __syncthreads();

    // ---- phase D: Dijkstra (wave 0 only; others idle at barriers) ----
    int np = nParkSh;
    for (int f = 0; f < np; ++f) {
        int curRow = parked[f];
        int asgCount = asgCountSh;
        double mvA = INF, mvB = INF;
        bool pA = false, pB = false;
        double bestFree = INF; int bfCol = -1, bfRow = -1;
        double minVal = 0.0; int i = curRow; int nSr = 1;
        if (w == 0) {
            for (int pos = lane; pos < asgCount; pos += 64) distA[pos] = INF;
            if (lane == 0) srList[0] = curRow;
        }
        __syncthreads();

        if (w == 0) {
            int g2 = 0; bool sink = false;
            while (!sink && g2++ < 120) {
                double ui = u[i];
                {
                    int pos = lane;
                    if (pos < asgCount && !pA) {
                        int j = asgCols[pos];
                        double cur = minVal + (double)Cb[(size_t)j * NT + i] - ui - vsh[j];
                        if (cur < mvA) { mvA = cur; distA[pos] = cur; pathA[pos] = i; }
                    }
                    pos = lane + 64;
                    if (pos < asgCount && !pB) {
                        int j = asgCols[pos];
                        double cur = minVal + (double)Cb[(size_t)j * NT + i] - ui - vsh[j];
                        if (cur < mvB) { mvB = cur; distA[pos] = cur; pathA[pos] = i; }
                    }
                }
                double fc = INF; int fj = -1;
                if (lane < K8) {
                    unsigned long long tk = tksh[i][lane];
                    int j = unpack_col(tk);
                    if (row4col[j] < 0) { fc = minVal + (double)unpack_val(tk) - ui; fj = j; }
                }
                if (__ballot(fc < INF) == 0ull) {
                    #pragma unroll
                    for (int k = 0; k < SLOTS; ++k) {
                        int j = (k << 6) + lane;
                        if (((k < SLOTS - 1) || (j < NQ)) && row4col[j] < 0) {
                            double cur = minVal + (double)Cb[(size_t)j * NT + i] - ui;
                            if (cur < fc) { fc = cur; fj = j; }
                        }
                    }
                }
                double pv; int ppos;
                double pva = pA ? INF : mvA, pvb = pB ? INF : mvB;
                if (pvb < pva) { pv = pvb; ppos = lane + 64; } else { pv = pva; ppos = lane; }
                for (int off = 32; off; off >>= 1) {
                    double o = __shfl_down(pv, off); int op = __shfl_down(ppos, off);
                    if (o < pv || (o == pv && op < ppos)) { pv = o; ppos = op; }
                    double of = __shfl_down(fc, off); int ofj = __shfl_down(fj, off);
                    if (of < fc || (of == fc && (unsigned)ofj < (unsigned)fj)) { fc = of; fj = ofj; }
                }
                pv = __shfl(pv, 0); ppos = __shfl(ppos, 0);
                fc = __shfl(fc, 0); fj = __shfl(fj, 0);
                if (fc < bestFree) { bestFree = fc; bfCol = fj; bfRow = i; }
                if (bestFree <= pv) { minVal = bestFree; sink = true; }
                else {
                    minVal = pv;
                    if (lane == (ppos & 63)) { if (ppos < 64) pA = true; else pB = true; }
                    i = row4col[asgCols[ppos]];
                    if (lane == 0) srList[nSr] = i;
                    nSr++;
                }
            }
            if (lane == 0) { pm1[0] = minVal; pj1[0] = bfCol; prow[0] = bfRow; pm2[0] = (double)nSr; }
        }
        __syncthreads();

        if (tid == 0) {
            double mv = pm1[0]; int ns = (int)pm2[0];
            u[curRow] += mv;
            for (int t2 = 1; t2 < ns; ++t2) {
                int ri = srList[t2];
                u[ri] += mv - distA[pos4col[col4row[ri]]];
            }
        }
        if (w == 0) {
            double mv = pm1[0];
            int pos = lane;
            if (pos < asgCount && pA) vsh[asgCols[pos]] -= mv - distA[pos];
            pos = lane + 64;
            if (pos < asgCount && pB) vsh[asgCols[pos]] -= mv - distA[pos];
        }
        if (tid == 0) {
            int j = pj1[0], ri = prow[0]; int g3 = 0;
            while (g3++ < 128) {
                row4col[j] = ri;
                int tj = col4row[ri]; col4row[ri] = j;
                if (ri == curRow) break;
                j = tj; ri = pathA[pos4col[j]];
            }
            pos4col[pj1[0]] = asgCountSh; asgCols[asgCountSh] = pj1[0]; asgCountSh++;
        }
        __syncthreads();
    }

    // ---- epilogue: rank-sort col4row, write indices ----
    for (int i2 = tid; i2 < NT; i2 += JBLK) {
        int ci = col4row[i2];
        int rank = 0;
        for (int k2 = 0; k2 < NT; ++k2) rank += (col4row[k2] < ci);
        pred_out[b * NT + rank] = (float)ci;
        tgt_out[b * NT + rank] = (float)i2;
    }
}

extern "C" void kernel_launch(void* const* d_in, const int* in_sizes, int n_in,
                              void* d_out, int out_size, void* d_ws, size_t ws_size,
                              hipStream_t stream) {
    const float* logits = (const float*)d_in[0];
    const float* boxes  = (const float*)d_in[1];
    const int*   tlab   = (const int*)d_in[2];
    const float* tboxes = (const float*)d_in[3];

    float* out  = (float*)d_out;
    float* C    = out;                                  // 32*900*100
    float* pred = out + (size_t)BS * NQ * NT;           // 32*100
    float* tgt  = pred + BS * NT;                       // 32*100

    cost_kernel<<<BS * NQ, 128, 0, stream>>>(logits, boxes, tlab, tboxes, C);
    transpose_kernel<<<BS * 15, 256, 0, stream>>>(C);
    topk_kernel<<<BS * NT, 64, 0, stream>>>();
    jv_kernel<<<BS, JBLK, 0, stream>>>(C, pred, tgt);
}